// Round 1
// baseline (335.224 us; speedup 1.0000x reference)
//
#include <hip/hip_runtime.h>
#include <hip/hip_bf16.h>

// ---------------- constants ----------------
#define F 128           // hidden width
#define NHID 7          // hidden 128->128 layers
#define LDH (F + 4)     // padded LDS row stride (floats), keeps 16B alignment
#define BP 64           // points per MLP block
#define NPTS 20000
#define CH_DB 20        // chamfer db chunks
#define QT 8            // queries per thread (chamfer)
#define QBLK (QT * 256) // 2048 queries per block
#define DTILE 256       // db points per LDS tile
#define TRUNC_ 2.0f

// ---------------- MLP: out = in + sign * mlp(in) ----------------
__global__ __launch_bounds__(256) void mlp_kernel(
    const float* __restrict__ inp,   // [N][3]
    const float* __restrict__ W0,    // [3][F]
    const float* __restrict__ b0,    // [F]
    const float* __restrict__ Wh,    // [NHID][F][F]
    const float* __restrict__ bh,    // [NHID][F]
    const float* __restrict__ Wl,    // [F][3]
    const float* __restrict__ bl,    // [3]
    float* __restrict__ outp,        // [N][3]
    float sign, int N)
{
    __shared__ float hA[BP * LDH];
    __shared__ float hB[BP * LDH];
    const int tid = threadIdx.x;
    const int jg = tid & 31;   // column group (4 cols)
    const int pg = tid >> 5;   // point group (8 pts)
    const int j0 = jg * 4;
    const int p0 = blockIdx.x * BP;

    // ---- layer 0: 3 -> 128 ----
    float4 wr0 = *(const float4*)(W0 + 0 * F + j0);
    float4 wr1 = *(const float4*)(W0 + 1 * F + j0);
    float4 wr2 = *(const float4*)(W0 + 2 * F + j0);
    float4 bb0 = *(const float4*)(b0 + j0);
#pragma unroll
    for (int p = 0; p < 8; ++p) {
        int gp = p0 + pg * 8 + p;
        int cp = gp < N ? gp : N - 1;
        float x0 = inp[cp * 3 + 0];
        float x1 = inp[cp * 3 + 1];
        float x2 = inp[cp * 3 + 2];
        float4 h;
        h.x = fmaf(x0, wr0.x, fmaf(x1, wr1.x, fmaf(x2, wr2.x, bb0.x)));
        h.y = fmaf(x0, wr0.y, fmaf(x1, wr1.y, fmaf(x2, wr2.y, bb0.y)));
        h.z = fmaf(x0, wr0.z, fmaf(x1, wr1.z, fmaf(x2, wr2.z, bb0.z)));
        h.w = fmaf(x0, wr0.w, fmaf(x1, wr1.w, fmaf(x2, wr2.w, bb0.w)));
        h.x = fmaxf(h.x, 0.f); h.y = fmaxf(h.y, 0.f);
        h.z = fmaxf(h.z, 0.f); h.w = fmaxf(h.w, 0.f);
        *(float4*)(hA + (pg * 8 + p) * LDH + j0) = h;
    }
    __syncthreads();

    // ---- hidden layers: 128 -> 128 ----
    float* hin = hA;
    float* hout = hB;
    for (int layer = 0; layer < NHID; ++layer) {
        const float* W = Wh + (size_t)layer * F * F;
        float4 bb = *(const float4*)(bh + layer * F + j0);
        float4 acc[8];
#pragma unroll
        for (int p = 0; p < 8; ++p) acc[p] = bb;
        for (int k = 0; k < F; k += 4) {
            float4 w0 = *(const float4*)(W + (k + 0) * F + j0);
            float4 w1 = *(const float4*)(W + (k + 1) * F + j0);
            float4 w2 = *(const float4*)(W + (k + 2) * F + j0);
            float4 w3 = *(const float4*)(W + (k + 3) * F + j0);
#pragma unroll
            for (int p = 0; p < 8; ++p) {
                float4 h4 = *(const float4*)(hin + (pg * 8 + p) * LDH + k);
                acc[p].x = fmaf(h4.x, w0.x, fmaf(h4.y, w1.x, fmaf(h4.z, w2.x, fmaf(h4.w, w3.x, acc[p].x))));
                acc[p].y = fmaf(h4.x, w0.y, fmaf(h4.y, w1.y, fmaf(h4.z, w2.y, fmaf(h4.w, w3.y, acc[p].y))));
                acc[p].z = fmaf(h4.x, w0.z, fmaf(h4.y, w1.z, fmaf(h4.z, w2.z, fmaf(h4.w, w3.z, acc[p].z))));
                acc[p].w = fmaf(h4.x, w0.w, fmaf(h4.y, w1.w, fmaf(h4.z, w2.w, fmaf(h4.w, w3.w, acc[p].w))));
            }
        }
#pragma unroll
        for (int p = 0; p < 8; ++p) {
            float4 r;
            r.x = fmaxf(acc[p].x, 0.f);
            r.y = fmaxf(acc[p].y, 0.f);
            r.z = fmaxf(acc[p].z, 0.f);
            r.w = fmaxf(acc[p].w, 0.f);
            *(float4*)(hout + (pg * 8 + p) * LDH + j0) = r;
        }
        __syncthreads();
        float* t = hin; hin = hout; hout = t;
    }

    // ---- final layer: 128 -> 3, out = in + sign*(h@Wl + bl) ----
    if (tid < 192) {
        int p = tid / 3;
        int c = tid - 3 * p;
        float acc = bl[c];
        for (int k = 0; k < F; ++k)
            acc = fmaf(hin[p * LDH + k], Wl[k * 3 + c], acc);
        int gp = p0 + p;
        if (gp < N)
            outp[gp * 3 + c] = inp[gp * 3 + c] + sign * acc;
    }
}

// ---------------- chamfer: per-chunk partial mins ----------------
// dir 0: P=A(pc0to1) Q=B(pc1); dir 1: P=B Q=A; dir 2: P=C(est) Q=D(pc0); dir 3: P=D Q=C
__global__ __launch_bounds__(256) void chamfer_kernel(
    const float* __restrict__ A, const float* __restrict__ B,
    const float* __restrict__ C, const float* __restrict__ D,
    float* __restrict__ minpart,  // [4][CH_DB][n]
    int n)
{
    const int dir = blockIdx.z;
    const float* P;
    const float* Q;
    if (dir == 0)      { P = A; Q = B; }
    else if (dir == 1) { P = B; Q = A; }
    else if (dir == 2) { P = C; Q = D; }
    else               { P = D; Q = C; }

    __shared__ float4 tile[DTILE];
    const int tid = threadIdx.x;
    const int qbase = blockIdx.x * QBLK;

    float px[QT], py[QT], pz[QT], mn[QT];
#pragma unroll
    for (int i = 0; i < QT; ++i) {
        int gq = qbase + i * 256 + tid;
        int cq = gq < n ? gq : 0;
        px[i] = P[cq * 3 + 0];
        py[i] = P[cq * 3 + 1];
        pz[i] = P[cq * 3 + 2];
        mn[i] = 3.4e38f;
    }

    const int chunk = (n + CH_DB - 1) / CH_DB;   // 1000
    const int db0 = blockIdx.y * chunk;
    const int db1 = min(db0 + chunk, n);

    for (int t0 = db0; t0 < db1; t0 += DTILE) {
        __syncthreads();
        int cnt = min(DTILE, db1 - t0);
        if (tid < cnt) {
            int gq = t0 + tid;
            float qx = Q[gq * 3 + 0];
            float qy = Q[gq * 3 + 1];
            float qz = Q[gq * 3 + 2];
            tile[tid] = make_float4(-2.f * qx, -2.f * qy, -2.f * qz,
                                    fmaf(qx, qx, fmaf(qy, qy, qz * qz)));
        }
        __syncthreads();
#pragma unroll 4
        for (int t = 0; t < cnt; ++t) {
            float4 q = tile[t];
#pragma unroll
            for (int i = 0; i < QT; ++i) {
                float s = fmaf(px[i], q.x, fmaf(py[i], q.y, fmaf(pz[i], q.z, q.w)));
                mn[i] = fminf(mn[i], s);
            }
        }
    }

    size_t base = ((size_t)dir * CH_DB + blockIdx.y) * (size_t)n;
#pragma unroll
    for (int i = 0; i < QT; ++i) {
        int gq = qbase + i * 256 + tid;
        if (gq < n) {
            float np_ = fmaf(px[i], px[i], fmaf(py[i], py[i], pz[i] * pz[i]));
            float d = np_ + mn[i];
            minpart[base + gq] = fmaxf(d, 0.0f);
        }
    }
}

// ---------------- reductions ----------------
__device__ inline float block_sum256(float v)
{
    __shared__ float sws[4];
#pragma unroll
    for (int o = 32; o > 0; o >>= 1) v += __shfl_down(v, o, 64);
    int w = threadIdx.x >> 6;
    if ((threadIdx.x & 63) == 0) sws[w] = v;
    __syncthreads();
    if (threadIdx.x == 0) v = sws[0] + sws[1] + sws[2] + sws[3];
    return v;
}

__global__ __launch_bounds__(256) void reduce1_kernel(
    const float* __restrict__ minpart,  // [4][CH_DB][n]
    float* __restrict__ partials, int n)
{
    float s = 0.f;
    int total = 4 * n;
    for (int idx = blockIdx.x * blockDim.x + threadIdx.x; idx < total;
         idx += gridDim.x * blockDim.x) {
        int dir = idx / n;
        int q = idx - dir * n;
        const float* base = minpart + (size_t)dir * CH_DB * n + q;
        float m = base[0];
#pragma unroll
        for (int c = 1; c < CH_DB; ++c) m = fminf(m, base[(size_t)c * n]);
        s += (m < TRUNC_) ? m : 0.0f;
    }
    float bs = block_sum256(s);
    if (threadIdx.x == 0) partials[blockIdx.x] = bs;
}

__global__ __launch_bounds__(256) void reduce2_kernel(
    const float* __restrict__ partials, int nb, float* __restrict__ out, float inv)
{
    float s = 0.f;
    for (int i = threadIdx.x; i < nb; i += blockDim.x) s += partials[i];
    float bs = block_sum256(s);
    if (threadIdx.x == 0) out[0] = bs * inv;
}

// ---------------- launch ----------------
extern "C" void kernel_launch(void* const* d_in, const int* in_sizes, int n_in,
                              void* d_out, int out_size, void* d_ws, size_t ws_size,
                              hipStream_t stream)
{
    const float* pc0 = (const float*)d_in[0];
    const float* pc1 = (const float*)d_in[1];
    const float* W0  = (const float*)d_in[2];
    const float* b0  = (const float*)d_in[3];
    const float* Wh  = (const float*)d_in[4];
    const float* bh  = (const float*)d_in[5];
    const float* Wl  = (const float*)d_in[6];
    const float* bl  = (const float*)d_in[7];
    const float* W0i = (const float*)d_in[8];
    const float* b0i = (const float*)d_in[9];
    const float* Whi = (const float*)d_in[10];
    const float* bhi = (const float*)d_in[11];
    const float* Wli = (const float*)d_in[12];
    const float* bli = (const float*)d_in[13];
    float* out = (float*)d_out;

    const int N = NPTS;
    float* ws = (float*)d_ws;
    float* A = ws;                       // pc0_to_pc1  [N*3]
    float* C = ws + (size_t)N * 3;       // est         [N*3]
    float* minpart = ws + (size_t)N * 6; // [4][CH_DB][N]
    float* partials = minpart + (size_t)4 * CH_DB * N;  // [80]

    const int NB1 = 80;

    int mlpg = (N + BP - 1) / BP;  // 313
    hipLaunchKernelGGL(mlp_kernel, dim3(mlpg), dim3(256), 0, stream,
                       pc0, W0, b0, Wh, bh, Wl, bl, A, 1.0f, N);
    hipLaunchKernelGGL(mlp_kernel, dim3(mlpg), dim3(256), 0, stream,
                       A, W0i, b0i, Whi, bhi, Wli, bli, C, -1.0f, N);

    dim3 cgrid((N + QBLK - 1) / QBLK, CH_DB, 4);  // (10, 20, 4)
    hipLaunchKernelGGL(chamfer_kernel, cgrid, dim3(256), 0, stream,
                       A, pc1, C, pc0, minpart, N);

    hipLaunchKernelGGL(reduce1_kernel, dim3(NB1), dim3(256), 0, stream,
                       minpart, partials, N);
    hipLaunchKernelGGL(reduce2_kernel, dim3(1), dim3(256), 0, stream,
                       partials, NB1, out, 1.0f / (float)N);
}

// Round 2
// 267.968 us; speedup vs baseline: 1.2510x; 1.2510x over previous
//
#include <hip/hip_runtime.h>
#include <hip/hip_bf16.h>

// ---------------- constants ----------------
#define F 128           // hidden width
#define NHID 7          // hidden 128->128 layers
#define LDH (F + 4)     // padded LDS row stride (floats)
#define BP 64           // points per MLP block
#define TRUNC_ 2.0f

// spatial grid: cell size must be >= sqrt(2) (truncation radius)
#define GM 48                  // cells per dimension
#define GM3 (GM * GM * GM)     // 110592
#define GLO (-42.0f)
#define GINV (1.0f / 1.75f)
#define SCAN_BLKS (GM3 / 256)  // 432 scan blocks per grid
#define NGRID 4

// ---------------- MLP: out = in + sign * mlp(in) ----------------
__global__ __launch_bounds__(256) void mlp_kernel(
    const float* __restrict__ inp,   // [N][3]
    const float* __restrict__ W0,    // [3][F]
    const float* __restrict__ b0,    // [F]
    const float* __restrict__ Wh,    // [NHID][F][F]
    const float* __restrict__ bh,    // [NHID][F]
    const float* __restrict__ Wl,    // [F][3]
    const float* __restrict__ bl,    // [3]
    float* __restrict__ outp,        // [N][3]
    float sign, int N)
{
    __shared__ float hA[BP * LDH];
    __shared__ float hB[BP * LDH];
    const int tid = threadIdx.x;
    const int jg = tid & 31;   // column group (4 cols)
    const int pg = tid >> 5;   // point group (8 pts)
    const int j0 = jg * 4;
    const int p0 = blockIdx.x * BP;

    // ---- layer 0: 3 -> 128 ----
    float4 wr0 = *(const float4*)(W0 + 0 * F + j0);
    float4 wr1 = *(const float4*)(W0 + 1 * F + j0);
    float4 wr2 = *(const float4*)(W0 + 2 * F + j0);
    float4 bb0 = *(const float4*)(b0 + j0);
#pragma unroll
    for (int p = 0; p < 8; ++p) {
        int gp = p0 + pg * 8 + p;
        int cp = gp < N ? gp : N - 1;
        float x0 = inp[cp * 3 + 0];
        float x1 = inp[cp * 3 + 1];
        float x2 = inp[cp * 3 + 2];
        float4 h;
        h.x = fmaf(x0, wr0.x, fmaf(x1, wr1.x, fmaf(x2, wr2.x, bb0.x)));
        h.y = fmaf(x0, wr0.y, fmaf(x1, wr1.y, fmaf(x2, wr2.y, bb0.y)));
        h.z = fmaf(x0, wr0.z, fmaf(x1, wr1.z, fmaf(x2, wr2.z, bb0.z)));
        h.w = fmaf(x0, wr0.w, fmaf(x1, wr1.w, fmaf(x2, wr2.w, bb0.w)));
        h.x = fmaxf(h.x, 0.f); h.y = fmaxf(h.y, 0.f);
        h.z = fmaxf(h.z, 0.f); h.w = fmaxf(h.w, 0.f);
        *(float4*)(hA + (pg * 8 + p) * LDH + j0) = h;
    }
    __syncthreads();

    // ---- hidden layers: 128 -> 128 ----
    float* hin = hA;
    float* hout = hB;
    for (int layer = 0; layer < NHID; ++layer) {
        const float* W = Wh + (size_t)layer * F * F;
        float4 bb = *(const float4*)(bh + layer * F + j0);
        float4 acc[8];
#pragma unroll
        for (int p = 0; p < 8; ++p) acc[p] = bb;
        for (int k = 0; k < F; k += 4) {
            float4 w0 = *(const float4*)(W + (k + 0) * F + j0);
            float4 w1 = *(const float4*)(W + (k + 1) * F + j0);
            float4 w2 = *(const float4*)(W + (k + 2) * F + j0);
            float4 w3 = *(const float4*)(W + (k + 3) * F + j0);
#pragma unroll
            for (int p = 0; p < 8; ++p) {
                float4 h4 = *(const float4*)(hin + (pg * 8 + p) * LDH + k);
                acc[p].x = fmaf(h4.x, w0.x, fmaf(h4.y, w1.x, fmaf(h4.z, w2.x, fmaf(h4.w, w3.x, acc[p].x))));
                acc[p].y = fmaf(h4.x, w0.y, fmaf(h4.y, w1.y, fmaf(h4.z, w2.y, fmaf(h4.w, w3.y, acc[p].y))));
                acc[p].z = fmaf(h4.x, w0.z, fmaf(h4.y, w1.z, fmaf(h4.z, w2.z, fmaf(h4.w, w3.z, acc[p].z))));
                acc[p].w = fmaf(h4.x, w0.w, fmaf(h4.y, w1.w, fmaf(h4.z, w2.w, fmaf(h4.w, w3.w, acc[p].w))));
            }
        }
#pragma unroll
        for (int p = 0; p < 8; ++p) {
            float4 r;
            r.x = fmaxf(acc[p].x, 0.f);
            r.y = fmaxf(acc[p].y, 0.f);
            r.z = fmaxf(acc[p].z, 0.f);
            r.w = fmaxf(acc[p].w, 0.f);
            *(float4*)(hout + (pg * 8 + p) * LDH + j0) = r;
        }
        __syncthreads();
        float* t = hin; hin = hout; hout = t;
    }

    // ---- final layer: 128 -> 3, out = in + sign*(h@Wl + bl) ----
    if (tid < 192) {
        int p = tid / 3;
        int c = tid - 3 * p;
        float acc = bl[c];
        for (int k = 0; k < F; ++k)
            acc = fmaf(hin[p * LDH + k], Wl[k * 3 + c], acc);
        int gp = p0 + p;
        if (gp < N)
            outp[gp * 3 + c] = inp[gp * 3 + c] + sign * acc;
    }
}

// ---------------- spatial grid helpers ----------------
__device__ inline int cell_of(float x, float y, float z)
{
    int cx = (int)floorf((x - GLO) * GINV);
    int cy = (int)floorf((y - GLO) * GINV);
    int cz = (int)floorf((z - GLO) * GINV);
    cx = min(max(cx, 0), GM - 1);
    cy = min(max(cy, 0), GM - 1);
    cz = min(max(cz, 0), GM - 1);
    return (cz * GM + cy) * GM + cx;
}

__device__ inline const float* cloud_ptr(int g, const float* g0, const float* g1,
                                         const float* g2, const float* g3)
{
    return g == 0 ? g0 : (g == 1 ? g1 : (g == 2 ? g2 : g3));
}

__global__ __launch_bounds__(256) void zero_counts(int* __restrict__ counts)
{
    counts[blockIdx.x * 256 + threadIdx.x] = 0;
}

// counts over 4 clouds: g0=pc1(B), g1=A, g2=pc0(D), g3=C
__global__ __launch_bounds__(256) void grid_count(
    const float* __restrict__ B, const float* __restrict__ A,
    const float* __restrict__ D, const float* __restrict__ C,
    int* __restrict__ counts, int n)
{
    int g = blockIdx.y;
    const float* P = cloud_ptr(g, B, A, D, C);
    int i = blockIdx.x * 256 + threadIdx.x;
    if (i < n) {
        float x = P[i * 3 + 0], y = P[i * 3 + 1], z = P[i * 3 + 2];
        atomicAdd(&counts[g * GM3 + cell_of(x, y, z)], 1);
    }
}

// exclusive scan, stage 1: per-256 block
__global__ __launch_bounds__(256) void scan1(
    const int* __restrict__ counts, int* __restrict__ offs, int* __restrict__ bsum)
{
    int tid = threadIdx.x;
    int i = blockIdx.x * 256 + tid;
    int v = counts[i];
    __shared__ int s[256];
    s[tid] = v;
    __syncthreads();
#pragma unroll
    for (int off = 1; off < 256; off <<= 1) {
        int t = (tid >= off) ? s[tid - off] : 0;
        __syncthreads();
        s[tid] += t;
        __syncthreads();
    }
    offs[i] = s[tid] - v;           // exclusive
    if (tid == 255) bsum[blockIdx.x] = s[255];
}

// stage 2: scan SCAN_BLKS block-sums per grid segment (one block per grid)
__global__ __launch_bounds__(256) void scan2(int* __restrict__ bsum)
{
    const int SEG = SCAN_BLKS;      // 432
    int base = blockIdx.x * SEG;
    int t = threadIdx.x;
    int i0 = 2 * t, i1 = 2 * t + 1;
    int e0 = (i0 < SEG) ? bsum[base + i0] : 0;
    int e1 = (i1 < SEG) ? bsum[base + i1] : 0;
    int sum = e0 + e1;
    __shared__ int s[256];
    s[t] = sum;
    __syncthreads();
#pragma unroll
    for (int off = 1; off < 256; off <<= 1) {
        int x = (t >= off) ? s[t - off] : 0;
        __syncthreads();
        s[t] += x;
        __syncthreads();
    }
    int excl = s[t] - sum;
    if (i0 < SEG) bsum[base + i0] = excl;
    if (i1 < SEG) bsum[base + i1] = excl + e0;
}

// stage 3: add scanned block sums back
__global__ __launch_bounds__(256) void scan3(int* __restrict__ offs, const int* __restrict__ bsum)
{
    int i = blockIdx.x * 256 + threadIdx.x;
    offs[i] += bsum[blockIdx.x];
}

// scatter points into sorted order (counts reused as cursors, re-zeroed before)
__global__ __launch_bounds__(256) void grid_fill(
    const float* __restrict__ B, const float* __restrict__ A,
    const float* __restrict__ D, const float* __restrict__ C,
    const int* __restrict__ offs, int* __restrict__ counts,
    float4* __restrict__ pts, int n)
{
    int g = blockIdx.y;
    const float* P = cloud_ptr(g, B, A, D, C);
    int i = blockIdx.x * 256 + threadIdx.x;
    if (i < n) {
        float x = P[i * 3 + 0], y = P[i * 3 + 1], z = P[i * 3 + 2];
        int c = g * GM3 + cell_of(x, y, z);
        int slot = offs[c] + atomicAdd(&counts[c], 1);
        pts[(size_t)g * n + slot] = make_float4(x, y, z, 0.f);
    }
}

// per-query truncated NN search: 27 cells = 9 contiguous x-ranges
__global__ __launch_bounds__(64) void grid_search(
    const float* __restrict__ A, const float* __restrict__ B,
    const float* __restrict__ C, const float* __restrict__ D,
    const int* __restrict__ offs, const int* __restrict__ counts,
    const float4* __restrict__ pts, float* __restrict__ mins, int n)
{
    int d = blockIdx.y;
    // d0: A vs grid(B)=g0; d1: B vs grid(A)=g1; d2: C vs grid(D)=g2; d3: D vs grid(C)=g3
    const float* Q = cloud_ptr(d, A, B, C, D);
    int g = d;
    int i = blockIdx.x * 64 + threadIdx.x;
    if (i >= n) return;
    float qx = Q[i * 3 + 0], qy = Q[i * 3 + 1], qz = Q[i * 3 + 2];
    int cx = min(max((int)floorf((qx - GLO) * GINV), 0), GM - 1);
    int cy = min(max((int)floorf((qy - GLO) * GINV), 0), GM - 1);
    int cz = min(max((int)floorf((qz - GLO) * GINV), 0), GM - 1);
    const int* ofs = offs + (size_t)g * GM3;
    const int* cnt = counts + (size_t)g * GM3;
    const float4* P = pts + (size_t)g * n;
    float mn = 3.4e38f;
    int x0 = max(cx - 1, 0), x1 = min(cx + 1, GM - 1);
#pragma unroll
    for (int dz = -1; dz <= 1; ++dz) {
        int z = cz + dz;
        if ((unsigned)z >= GM) continue;
#pragma unroll
        for (int dy = -1; dy <= 1; ++dy) {
            int y = cy + dy;
            if ((unsigned)y >= GM) continue;
            int rowbase = (z * GM + y) * GM;
            int o = ofs[rowbase + x0];
            int e = ofs[rowbase + x1] + cnt[rowbase + x1];
            for (int k = o; k < e; ++k) {
                float4 p = P[k];
                float ddx = qx - p.x, ddy = qy - p.y, ddz = qz - p.z;
                float dd = fmaf(ddx, ddx, fmaf(ddy, ddy, ddz * ddz));
                mn = fminf(mn, dd);
            }
        }
    }
    mins[(size_t)d * n + i] = (mn < TRUNC_) ? mn : 0.f;
}

// ---------------- reductions ----------------
__device__ inline float block_sum256(float v)
{
    __shared__ float sws[4];
#pragma unroll
    for (int o = 32; o > 0; o >>= 1) v += __shfl_down(v, o, 64);
    int w = threadIdx.x >> 6;
    if ((threadIdx.x & 63) == 0) sws[w] = v;
    __syncthreads();
    if (threadIdx.x == 0) v = sws[0] + sws[1] + sws[2] + sws[3];
    return v;
}

__global__ __launch_bounds__(256) void reduce1_kernel(
    const float* __restrict__ mins, float* __restrict__ partials, int total)
{
    float s = 0.f;
    for (int idx = blockIdx.x * blockDim.x + threadIdx.x; idx < total;
         idx += gridDim.x * blockDim.x)
        s += mins[idx];
    float bs = block_sum256(s);
    if (threadIdx.x == 0) partials[blockIdx.x] = bs;
}

__global__ __launch_bounds__(256) void reduce2_kernel(
    const float* __restrict__ partials, int nb, float* __restrict__ out, float inv)
{
    float s = 0.f;
    for (int i = threadIdx.x; i < nb; i += blockDim.x) s += partials[i];
    float bs = block_sum256(s);
    if (threadIdx.x == 0) out[0] = bs * inv;
}

// ---------------- launch ----------------
extern "C" void kernel_launch(void* const* d_in, const int* in_sizes, int n_in,
                              void* d_out, int out_size, void* d_ws, size_t ws_size,
                              hipStream_t stream)
{
    const float* pc0 = (const float*)d_in[0];
    const float* pc1 = (const float*)d_in[1];
    const float* W0  = (const float*)d_in[2];
    const float* b0  = (const float*)d_in[3];
    const float* Wh  = (const float*)d_in[4];
    const float* bh  = (const float*)d_in[5];
    const float* Wl  = (const float*)d_in[6];
    const float* bl  = (const float*)d_in[7];
    const float* W0i = (const float*)d_in[8];
    const float* b0i = (const float*)d_in[9];
    const float* Whi = (const float*)d_in[10];
    const float* bhi = (const float*)d_in[11];
    const float* Wli = (const float*)d_in[12];
    const float* bli = (const float*)d_in[13];
    float* out = (float*)d_out;

    const int N = in_sizes[0] / 3;   // 20000

    // ws layout (bytes)
    char* base = (char*)d_ws;
    float*  A        = (float*)(base);                        // N*3 f32
    float*  C        = (float*)(base + 240000);               // N*3 f32
    int*    counts   = (int*)  (base + 480000);               // 4*GM3
    int*    offs     = (int*)  (base + 480000 + 4u*GM3*4);    // 4*GM3
    int*    bsum     = (int*)  (base + 480000 + 8u*GM3*4);    // 4*SCAN_BLKS
    float4* pts      = (float4*)(base + 480000 + 8u*GM3*4 + 6912); // 4*N float4
    float*  mins     = (float*)(base + 480000 + 8u*GM3*4 + 6912 + (size_t)4*N*16);
    float*  partials = mins + (size_t)4 * N;                  // 80

    const int NB1 = 80;
    const int PB = (N + 255) / 256;        // 79 point-blocks
    const int SB = (N + 63) / 64;          // 313 search-blocks
    const int ZB = NGRID * GM3 / 256;      // 1728 zero/scan blocks

    int mlpg = (N + BP - 1) / BP;  // 313
    hipLaunchKernelGGL(mlp_kernel, dim3(mlpg), dim3(256), 0, stream,
                       pc0, W0, b0, Wh, bh, Wl, bl, A, 1.0f, N);
    hipLaunchKernelGGL(mlp_kernel, dim3(mlpg), dim3(256), 0, stream,
                       A, W0i, b0i, Whi, bhi, Wli, bli, C, -1.0f, N);

    // build 4 grids: g0=pc1, g1=A, g2=pc0, g3=C
    hipLaunchKernelGGL(zero_counts, dim3(ZB), dim3(256), 0, stream, counts);
    hipLaunchKernelGGL(grid_count, dim3(PB, NGRID), dim3(256), 0, stream,
                       pc1, A, pc0, C, counts, N);
    hipLaunchKernelGGL(scan1, dim3(ZB), dim3(256), 0, stream, counts, offs, bsum);
    hipLaunchKernelGGL(zero_counts, dim3(ZB), dim3(256), 0, stream, counts);
    hipLaunchKernelGGL(scan2, dim3(NGRID), dim3(256), 0, stream, bsum);
    hipLaunchKernelGGL(scan3, dim3(ZB), dim3(256), 0, stream, offs, bsum);
    hipLaunchKernelGGL(grid_fill, dim3(PB, NGRID), dim3(256), 0, stream,
                       pc1, A, pc0, C, offs, counts, pts, N);

    // truncated NN search, all 4 directions
    hipLaunchKernelGGL(grid_search, dim3(SB, NGRID), dim3(64), 0, stream,
                       A, pc1, C, pc0, offs, counts, pts, mins, N);

    hipLaunchKernelGGL(reduce1_kernel, dim3(NB1), dim3(256), 0, stream,
                       mins, partials, 4 * N);
    hipLaunchKernelGGL(reduce2_kernel, dim3(1), dim3(256), 0, stream,
                       partials, NB1, out, 1.0f / (float)N);
}

// Round 3
// 247.506 us; speedup vs baseline: 1.3544x; 1.0827x over previous
//
#include <hip/hip_runtime.h>
#include <hip/hip_bf16.h>

// ---------------- constants ----------------
#define F 128           // hidden width
#define NHID 7          // hidden 128->128 layers
#define BP 64           // points per MLP block
#define LDB 136         // LDS h row stride in ushorts (272 B = 17*16, 16B-aligned, conflict-free b128 reads)
#define TRUNC_ 2.0f

// spatial grid: cell size must be >= sqrt(2) (truncation radius)
#define GM 48                  // cells per dimension
#define GM3 (GM * GM * GM)     // 110592
#define GLO (-42.0f)
#define GINV (1.0f / 1.75f)
#define SCAN_BLKS (GM3 / 256)  // 432 scan blocks per grid
#define NGRID 4

typedef __attribute__((ext_vector_type(8))) short short8v;
typedef __attribute__((ext_vector_type(4))) float f32x4;

__device__ inline unsigned short f2bf(float v)
{
    __hip_bfloat16 b = __float2bfloat16(v);
    return __builtin_bit_cast(unsigned short, b);
}
__device__ inline float bf2f(unsigned short u)
{
    unsigned int x = ((unsigned int)u) << 16;
    return __builtin_bit_cast(float, x);
}

// ---------------- weight pre-pack: fp32 W[128][128] -> MFMA B-frag hi/lo ----------------
// dest idx = (((m*4 + s)*8 + n)*64 + lane)*8 + j  <-  W[m][k][c], k=s*32+(lane>>4)*8+j, c=n*16+(lane&15)
__global__ __launch_bounds__(256) void pack_w_kernel(
    const float* __restrict__ Wh, const float* __restrict__ Whi,
    unsigned short* __restrict__ whp, unsigned short* __restrict__ wlp)
{
    int idx = blockIdx.x * 256 + threadIdx.x;   // 14*4*8*64*8 = 229376 exactly
    int j = idx & 7;
    int l = (idx >> 3) & 63;
    int n = (idx >> 9) & 7;
    int s = (idx >> 12) & 3;
    int m = idx >> 14;                          // 0..13 : mlp*7 + layer
    int k = s * 32 + (l >> 4) * 8 + j;
    int c = n * 16 + (l & 15);
    const float* W = (m < 7 ? Wh + (size_t)m * F * F
                            : Whi + (size_t)(m - 7) * F * F);
    float w = W[k * F + c];
    unsigned short hi = f2bf(w);
    unsigned short lo = f2bf(w - bf2f(hi));
    whp[idx] = hi;
    wlp[idx] = lo;
}

// ---------------- MLP via MFMA (hi/lo bf16 split): out = in + sign * mlp(in) ----------------
__global__ __launch_bounds__(256) void mlp_mfma_kernel(
    const float* __restrict__ inp,   // [N][3]
    const float* __restrict__ W0,    // [3][F] fp32
    const float* __restrict__ b0,    // [F]
    const unsigned short* __restrict__ whp,  // packed B-frags hi, 7 layers
    const unsigned short* __restrict__ wlp,  // packed B-frags lo
    const float* __restrict__ bh,    // [NHID][F]
    const float* __restrict__ Wl,    // [F][3] fp32
    const float* __restrict__ bl,    // [3]
    float* __restrict__ outp,        // [N][3]
    float sign, int N)
{
    __shared__ unsigned short hhi[BP * LDB];
    __shared__ unsigned short hlo[BP * LDB];
    const int tid = threadIdx.x;
    const int lane = tid & 63;
    const int wv = tid >> 6;          // wave id 0..3 -> points wv*16..+16
    const int p0 = blockIdx.x * BP;

    // ---- layer 0 (3->128) on VALU, write hi/lo to LDS ----
    {
        const int jg = tid & 31;      // 4 cols
        const int pg = tid >> 5;      // 8 pts
        const int j0 = jg * 4;
        float4 wr0 = *(const float4*)(W0 + 0 * F + j0);
        float4 wr1 = *(const float4*)(W0 + 1 * F + j0);
        float4 wr2 = *(const float4*)(W0 + 2 * F + j0);
        float4 bb0 = *(const float4*)(b0 + j0);
#pragma unroll
        for (int p = 0; p < 8; ++p) {
            int gp = p0 + pg * 8 + p;
            int cp = gp < N ? gp : N - 1;
            float x0 = inp[cp * 3 + 0];
            float x1 = inp[cp * 3 + 1];
            float x2 = inp[cp * 3 + 2];
            float hx = fmaxf(fmaf(x0, wr0.x, fmaf(x1, wr1.x, fmaf(x2, wr2.x, bb0.x))), 0.f);
            float hy = fmaxf(fmaf(x0, wr0.y, fmaf(x1, wr1.y, fmaf(x2, wr2.y, bb0.y))), 0.f);
            float hz = fmaxf(fmaf(x0, wr0.z, fmaf(x1, wr1.z, fmaf(x2, wr2.z, bb0.z))), 0.f);
            float hw = fmaxf(fmaf(x0, wr0.w, fmaf(x1, wr1.w, fmaf(x2, wr2.w, bb0.w))), 0.f);
            unsigned short h0 = f2bf(hx), h1 = f2bf(hy), h2 = f2bf(hz), h3 = f2bf(hw);
            short4 hv = make_short4((short)h0, (short)h1, (short)h2, (short)h3);
            short4 lv = make_short4((short)f2bf(hx - bf2f(h0)), (short)f2bf(hy - bf2f(h1)),
                                    (short)f2bf(hz - bf2f(h2)), (short)f2bf(hw - bf2f(h3)));
            int pt = pg * 8 + p;
            *(short4*)&hhi[pt * LDB + j0] = hv;
            *(short4*)&hlo[pt * LDB + j0] = lv;
        }
    }
    __syncthreads();

    // ---- hidden layers via MFMA ----
    const int arow = lane & 15;   // A row (point within wave tile) == C col (feature)
    const int kg = lane >> 4;     // k-group / C row-group

    for (int layer = 0; layer < NHID; ++layer) {
        // A-frags for all 4 k-steps (this wave's 16 points)
        short8v ahi[4], alo[4];
#pragma unroll
        for (int s = 0; s < 4; ++s) {
            int pt = wv * 16 + arow;
            int k0 = s * 32 + kg * 8;
            ahi[s] = *(const short8v*)&hhi[pt * LDB + k0];
            alo[s] = *(const short8v*)&hlo[pt * LDB + k0];
        }
        __syncthreads();   // h fully consumed; safe to overwrite below

        // acc init with bias (per output feature = C col)
        f32x4 acc[8];
#pragma unroll
        for (int n = 0; n < 8; ++n) {
            float b = bh[layer * F + n * 16 + arow];
            acc[n] = (f32x4){b, b, b, b};
        }

        const unsigned short* whL = whp + (size_t)layer * (4 * 8 * 64 * 8);
        const unsigned short* wlL = wlp + (size_t)layer * (4 * 8 * 64 * 8);
#pragma unroll
        for (int s = 0; s < 4; ++s) {
#pragma unroll
            for (int n = 0; n < 8; ++n) {
                size_t off = ((size_t)((s * 8 + n) * 64 + lane)) * 8;
                short8v bhiF = *(const short8v*)(whL + off);
                short8v bloF = *(const short8v*)(wlL + off);
                acc[n] = __builtin_amdgcn_mfma_f32_16x16x32_bf16(ahi[s], bhiF, acc[n], 0, 0, 0);
                acc[n] = __builtin_amdgcn_mfma_f32_16x16x32_bf16(alo[s], bhiF, acc[n], 0, 0, 0);
                acc[n] = __builtin_amdgcn_mfma_f32_16x16x32_bf16(ahi[s], bloF, acc[n], 0, 0, 0);
            }
        }

        // ReLU + hi/lo split + write back to LDS
#pragma unroll
        for (int n = 0; n < 8; ++n) {
#pragma unroll
            for (int r = 0; r < 4; ++r) {
                float v = fmaxf(acc[n][r], 0.f);
                unsigned short hi = f2bf(v);
                unsigned short lo = f2bf(v - bf2f(hi));
                int pt = wv * 16 + kg * 4 + r;
                int ft = n * 16 + arow;
                hhi[pt * LDB + ft] = hi;
                hlo[pt * LDB + ft] = lo;
            }
        }
        __syncthreads();
    }

    // ---- final layer 128->3 on VALU ----
    if (tid < 192) {
        int p = tid / 3;
        int c = tid - 3 * p;
        float acc = bl[c];
        for (int k0 = 0; k0 < F; k0 += 8) {
            short8v h8 = *(const short8v*)&hhi[p * LDB + k0];
            short8v l8 = *(const short8v*)&hlo[p * LDB + k0];
#pragma unroll
            for (int j = 0; j < 8; ++j) {
                float hv = bf2f((unsigned short)h8[j]) + bf2f((unsigned short)l8[j]);
                acc = fmaf(hv, Wl[(k0 + j) * 3 + c], acc);
            }
        }
        int gp = p0 + p;
        if (gp < N)
            outp[gp * 3 + c] = inp[gp * 3 + c] + sign * acc;
    }
}

// ---------------- spatial grid helpers ----------------
__device__ inline int cell_of(float x, float y, float z)
{
    int cx = (int)floorf((x - GLO) * GINV);
    int cy = (int)floorf((y - GLO) * GINV);
    int cz = (int)floorf((z - GLO) * GINV);
    cx = min(max(cx, 0), GM - 1);
    cy = min(max(cy, 0), GM - 1);
    cz = min(max(cz, 0), GM - 1);
    return (cz * GM + cy) * GM + cx;
}

__device__ inline const float* cloud_ptr(int g, const float* g0, const float* g1,
                                         const float* g2, const float* g3)
{
    return g == 0 ? g0 : (g == 1 ? g1 : (g == 2 ? g2 : g3));
}

__global__ __launch_bounds__(256) void zero_counts(int* __restrict__ counts)
{
    counts[blockIdx.x * 256 + threadIdx.x] = 0;
}

__global__ __launch_bounds__(256) void grid_count(
    const float* __restrict__ B, const float* __restrict__ A,
    const float* __restrict__ D, const float* __restrict__ C,
    int* __restrict__ counts, int n)
{
    int g = blockIdx.y;
    const float* P = cloud_ptr(g, B, A, D, C);
    int i = blockIdx.x * 256 + threadIdx.x;
    if (i < n) {
        float x = P[i * 3 + 0], y = P[i * 3 + 1], z = P[i * 3 + 2];
        atomicAdd(&counts[g * GM3 + cell_of(x, y, z)], 1);
    }
}

__global__ __launch_bounds__(256) void scan1(
    const int* __restrict__ counts, int* __restrict__ offs, int* __restrict__ bsum)
{
    int tid = threadIdx.x;
    int i = blockIdx.x * 256 + tid;
    int v = counts[i];
    __shared__ int s[256];
    s[tid] = v;
    __syncthreads();
#pragma unroll
    for (int off = 1; off < 256; off <<= 1) {
        int t = (tid >= off) ? s[tid - off] : 0;
        __syncthreads();
        s[tid] += t;
        __syncthreads();
    }
    offs[i] = s[tid] - v;           // exclusive
    if (tid == 255) bsum[blockIdx.x] = s[255];
}

__global__ __launch_bounds__(256) void scan2(int* __restrict__ bsum)
{
    const int SEG = SCAN_BLKS;      // 432
    int base = blockIdx.x * SEG;
    int t = threadIdx.x;
    int i0 = 2 * t, i1 = 2 * t + 1;
    int e0 = (i0 < SEG) ? bsum[base + i0] : 0;
    int e1 = (i1 < SEG) ? bsum[base + i1] : 0;
    int sum = e0 + e1;
    __shared__ int s[256];
    s[t] = sum;
    __syncthreads();
#pragma unroll
    for (int off = 1; off < 256; off <<= 1) {
        int x = (t >= off) ? s[t - off] : 0;
        __syncthreads();
        s[t] += x;
        __syncthreads();
    }
    int excl = s[t] - sum;
    if (i0 < SEG) bsum[base + i0] = excl;
    if (i1 < SEG) bsum[base + i1] = excl + e0;
}

// scan3 also re-zeros counts (cursors for grid_fill)
__global__ __launch_bounds__(256) void scan3(
    int* __restrict__ offs, const int* __restrict__ bsum, int* __restrict__ counts)
{
    int i = blockIdx.x * 256 + threadIdx.x;
    offs[i] += bsum[blockIdx.x];
    counts[i] = 0;
}

__global__ __launch_bounds__(256) void grid_fill(
    const float* __restrict__ B, const float* __restrict__ A,
    const float* __restrict__ D, const float* __restrict__ C,
    const int* __restrict__ offs, int* __restrict__ counts,
    float4* __restrict__ pts, int n)
{
    int g = blockIdx.y;
    const float* P = cloud_ptr(g, B, A, D, C);
    int i = blockIdx.x * 256 + threadIdx.x;
    if (i < n) {
        float x = P[i * 3 + 0], y = P[i * 3 + 1], z = P[i * 3 + 2];
        int c = g * GM3 + cell_of(x, y, z);
        int slot = offs[c] + atomicAdd(&counts[c], 1);
        pts[(size_t)g * n + slot] = make_float4(x, y, z, 0.f);
    }
}

__global__ __launch_bounds__(64) void grid_search(
    const float* __restrict__ A, const float* __restrict__ B,
    const float* __restrict__ C, const float* __restrict__ D,
    const int* __restrict__ offs, const int* __restrict__ counts,
    const float4* __restrict__ pts, float* __restrict__ mins, int n)
{
    int d = blockIdx.y;
    const float* Q = cloud_ptr(d, A, B, C, D);
    int g = d;
    int i = blockIdx.x * 64 + threadIdx.x;
    if (i >= n) return;
    float qx = Q[i * 3 + 0], qy = Q[i * 3 + 1], qz = Q[i * 3 + 2];
    int cx = min(max((int)floorf((qx - GLO) * GINV), 0), GM - 1);
    int cy = min(max((int)floorf((qy - GLO) * GINV), 0), GM - 1);
    int cz = min(max((int)floorf((qz - GLO) * GINV), 0), GM - 1);
    const int* ofs = offs + (size_t)g * GM3;
    const int* cnt = counts + (size_t)g * GM3;
    const float4* P = pts + (size_t)g * n;
    float mn = 3.4e38f;
    int x0 = max(cx - 1, 0), x1 = min(cx + 1, GM - 1);
#pragma unroll
    for (int dz = -1; dz <= 1; ++dz) {
        int z = cz + dz;
        if ((unsigned)z >= GM) continue;
#pragma unroll
        for (int dy = -1; dy <= 1; ++dy) {
            int y = cy + dy;
            if ((unsigned)y >= GM) continue;
            int rowbase = (z * GM + y) * GM;
            int o = ofs[rowbase + x0];
            int e = ofs[rowbase + x1] + cnt[rowbase + x1];
            for (int k = o; k < e; ++k) {
                float4 p = P[k];
                float ddx = qx - p.x, ddy = qy - p.y, ddz = qz - p.z;
                float dd = fmaf(ddx, ddx, fmaf(ddy, ddy, ddz * ddz));
                mn = fminf(mn, dd);
            }
        }
    }
    mins[(size_t)d * n + i] = (mn < TRUNC_) ? mn : 0.f;
}

// ---------------- reductions ----------------
__device__ inline float block_sum256(float v)
{
    __shared__ float sws[4];
#pragma unroll
    for (int o = 32; o > 0; o >>= 1) v += __shfl_down(v, o, 64);
    int w = threadIdx.x >> 6;
    if ((threadIdx.x & 63) == 0) sws[w] = v;
    __syncthreads();
    if (threadIdx.x == 0) v = sws[0] + sws[1] + sws[2] + sws[3];
    return v;
}

__global__ __launch_bounds__(256) void reduce1_kernel(
    const float* __restrict__ mins, float* __restrict__ partials, int total)
{
    float s = 0.f;
    for (int idx = blockIdx.x * blockDim.x + threadIdx.x; idx < total;
         idx += gridDim.x * blockDim.x)
        s += mins[idx];
    float bs = block_sum256(s);
    if (threadIdx.x == 0) partials[blockIdx.x] = bs;
}

__global__ __launch_bounds__(256) void reduce2_kernel(
    const float* __restrict__ partials, int nb, float* __restrict__ out, float inv)
{
    float s = 0.f;
    for (int i = threadIdx.x; i < nb; i += blockDim.x) s += partials[i];
    float bs = block_sum256(s);
    if (threadIdx.x == 0) out[0] = bs * inv;
}

// ---------------- launch ----------------
extern "C" void kernel_launch(void* const* d_in, const int* in_sizes, int n_in,
                              void* d_out, int out_size, void* d_ws, size_t ws_size,
                              hipStream_t stream)
{
    const float* pc0 = (const float*)d_in[0];
    const float* pc1 = (const float*)d_in[1];
    const float* W0  = (const float*)d_in[2];
    const float* b0  = (const float*)d_in[3];
    const float* Wh  = (const float*)d_in[4];
    const float* bh  = (const float*)d_in[5];
    const float* Wl  = (const float*)d_in[6];
    const float* bl  = (const float*)d_in[7];
    const float* W0i = (const float*)d_in[8];
    const float* b0i = (const float*)d_in[9];
    const float* Whi = (const float*)d_in[10];
    const float* bhi = (const float*)d_in[11];
    const float* Wli = (const float*)d_in[12];
    const float* bli = (const float*)d_in[13];
    float* out = (float*)d_out;

    const int N = in_sizes[0] / 3;   // 20000

    // ws layout (byte offsets)
    char* base = (char*)d_ws;
    float*  A        = (float*)(base + 0);               // 240000
    float*  C        = (float*)(base + 240000);          // 240000
    int*    counts   = (int*)  (base + 480000);          // 1769472
    int*    offs     = (int*)  (base + 2249472);         // 1769472
    int*    bsum     = (int*)  (base + 4018944);         // 6912
    float4* pts      = (float4*)(base + 4025856);        // 1280000
    float*  mins     = (float*)(base + 5305856);         // 320000
    float*  partials = (float*)(base + 5625856);         // 320
    unsigned short* whp = (unsigned short*)(base + 5626176); // 458752
    unsigned short* wlp = (unsigned short*)(base + 6084928); // 458752

    const int NB1 = 80;
    const int PB = (N + 255) / 256;        // 79
    const int SB = (N + 63) / 64;          // 313
    const int ZB = NGRID * GM3 / 256;      // 1728
    const int PACKB = (14 * 4 * 8 * 64 * 8) / 256;  // 896

    // pack weights into MFMA B-frag hi/lo order (both MLPs)
    hipLaunchKernelGGL(pack_w_kernel, dim3(PACKB), dim3(256), 0, stream,
                       Wh, Whi, whp, wlp);

    int mlpg = (N + BP - 1) / BP;  // 313
    hipLaunchKernelGGL(mlp_mfma_kernel, dim3(mlpg), dim3(256), 0, stream,
                       pc0, W0, b0, whp, wlp, bh, Wl, bl, A, 1.0f, N);
    hipLaunchKernelGGL(mlp_mfma_kernel, dim3(mlpg), dim3(256), 0, stream,
                       A, W0i, b0i, whp + 7 * 16384, wlp + 7 * 16384, bhi, Wli, bli,
                       C, -1.0f, N);

    // build 4 grids: g0=pc1, g1=A, g2=pc0, g3=C
    hipLaunchKernelGGL(zero_counts, dim3(ZB), dim3(256), 0, stream, counts);
    hipLaunchKernelGGL(grid_count, dim3(PB, NGRID), dim3(256), 0, stream,
                       pc1, A, pc0, C, counts, N);
    hipLaunchKernelGGL(scan1, dim3(ZB), dim3(256), 0, stream, counts, offs, bsum);
    hipLaunchKernelGGL(scan2, dim3(NGRID), dim3(256), 0, stream, bsum);
    hipLaunchKernelGGL(scan3, dim3(ZB), dim3(256), 0, stream, offs, bsum, counts);
    hipLaunchKernelGGL(grid_fill, dim3(PB, NGRID), dim3(256), 0, stream,
                       pc1, A, pc0, C, offs, counts, pts, N);

    hipLaunchKernelGGL(grid_search, dim3(SB, NGRID), dim3(64), 0, stream,
                       A, pc1, C, pc0, offs, counts, pts, mins, N);

    hipLaunchKernelGGL(reduce1_kernel, dim3(NB1), dim3(256), 0, stream,
                       mins, partials, 4 * N);
    hipLaunchKernelGGL(reduce2_kernel, dim3(1), dim3(256), 0, stream,
                       partials, NB1, out, 1.0f / (float)N);
}

// Round 4
// 176.175 us; speedup vs baseline: 1.9028x; 1.4049x over previous
//
#include <hip/hip_runtime.h>
#include <hip/hip_bf16.h>

// ---------------- constants ----------------
#define F 128           // hidden width
#define NHID 7          // hidden 128->128 layers
#define BP 64           // points per MLP block
#define LDB 136         // LDS h row stride in ushorts (272 B, 16B-aligned)
#define TRUNC_ 2.0f

// spatial grid: cell size must be >= sqrt(2) (truncation radius)
#define GM 48                  // cells per dimension
#define GM3 (GM * GM * GM)     // 110592
#define GLO (-42.0f)
#define GINV (1.0f / 1.75f)
#define SCAN_BLKS (GM3 / 256)  // 432 scan blocks per grid
#define NGRID 4

typedef __attribute__((ext_vector_type(8))) short short8v;
typedef __attribute__((ext_vector_type(4))) float f32x4;

__device__ inline unsigned short f2bf(float v)
{
    __hip_bfloat16 b = __float2bfloat16(v);
    return __builtin_bit_cast(unsigned short, b);
}
__device__ inline float bf2f(unsigned short u)
{
    unsigned int x = ((unsigned int)u) << 16;
    return __builtin_bit_cast(float, x);
}

// ---------------- weight pre-pack: fp32 W[128][128] -> MFMA A-frag (W^T) hi/lo ----------------
// dest idx = (((m*4 + s)*8 + t)*64 + lane)*8 + j  <-  W[k][c], k=s*32+(lane>>4)*8+j, c=t*16+(lane&15)
// (identical layout works as A-operand frag of W^T: A[row=c][k])
__global__ __launch_bounds__(256) void pack_w_kernel(
    const float* __restrict__ Wh, const float* __restrict__ Whi,
    unsigned short* __restrict__ whp, unsigned short* __restrict__ wlp)
{
    int idx = blockIdx.x * 256 + threadIdx.x;   // 14*4*8*64*8 = 229376 exactly
    int j = idx & 7;
    int l = (idx >> 3) & 63;
    int t = (idx >> 9) & 7;
    int s = (idx >> 12) & 3;
    int m = idx >> 14;                          // 0..13 : mlp*7 + layer
    int k = s * 32 + (l >> 4) * 8 + j;
    int c = t * 16 + (l & 15);
    const float* W = (m < 7 ? Wh + (size_t)m * F * F
                            : Whi + (size_t)(m - 7) * F * F);
    float w = W[k * F + c];
    unsigned short hi = f2bf(w);
    unsigned short lo = f2bf(w - bf2f(hi));
    whp[idx] = hi;
    wlp[idx] = lo;
}

// ---------------- MLP via MFMA, 16 waves/block, f_out split across waves ----------------
// out = in + sign * mlp(in)
__global__ __launch_bounds__(1024) void mlp_mfma_kernel(
    const float* __restrict__ inp,   // [N][3]
    const float* __restrict__ W0,    // [3][F] fp32
    const float* __restrict__ b0,    // [F]
    const unsigned short* __restrict__ whp,  // packed W^T A-frags hi, 7 layers
    const unsigned short* __restrict__ wlp,  // packed lo
    const float* __restrict__ bh,    // [NHID][F]
    const float* __restrict__ Wl,    // [F][3] fp32
    const float* __restrict__ bl,    // [3]
    float* __restrict__ outp,        // [N][3]
    float sign, int N)
{
    __shared__ unsigned short h0h[BP * LDB];
    __shared__ unsigned short h0l[BP * LDB];
    __shared__ unsigned short h1h[BP * LDB];
    __shared__ unsigned short h1l[BP * LDB];

    const int tid = threadIdx.x;
    const int lane = tid & 63;
    const int wv = tid >> 6;          // 0..15
    const int ptile = wv & 3;         // N-tile: points ptile*16..+16
    const int fg = wv >> 2;           // f-group: mtiles {2fg, 2fg+1}
    const int arow = lane & 15;       // B col (point) / A row (f_out)
    const int kg = lane >> 4;         // k-group / C row-group
    const int p0 = blockIdx.x * BP;

    // ---- layer 0 (3->128) on VALU: 1024 threads, 2 pts each ----
    {
        const int jg = tid & 31;      // 4 cols
        const int pg = tid >> 5;      // 0..31 -> pts 2*pg, 2*pg+1
        const int j0 = jg * 4;
        float4 wr0 = *(const float4*)(W0 + 0 * F + j0);
        float4 wr1 = *(const float4*)(W0 + 1 * F + j0);
        float4 wr2 = *(const float4*)(W0 + 2 * F + j0);
        float4 bb0 = *(const float4*)(b0 + j0);
#pragma unroll
        for (int p = 0; p < 2; ++p) {
            int pt = pg * 2 + p;
            int gp = p0 + pt;
            int cp = gp < N ? gp : N - 1;
            float x0 = inp[cp * 3 + 0];
            float x1 = inp[cp * 3 + 1];
            float x2 = inp[cp * 3 + 2];
            float hx = fmaxf(fmaf(x0, wr0.x, fmaf(x1, wr1.x, fmaf(x2, wr2.x, bb0.x))), 0.f);
            float hy = fmaxf(fmaf(x0, wr0.y, fmaf(x1, wr1.y, fmaf(x2, wr2.y, bb0.y))), 0.f);
            float hz = fmaxf(fmaf(x0, wr0.z, fmaf(x1, wr1.z, fmaf(x2, wr2.z, bb0.z))), 0.f);
            float hw = fmaxf(fmaf(x0, wr0.w, fmaf(x1, wr1.w, fmaf(x2, wr2.w, bb0.w))), 0.f);
            unsigned short a0 = f2bf(hx), a1 = f2bf(hy), a2 = f2bf(hz), a3 = f2bf(hw);
            short4 hv = make_short4((short)a0, (short)a1, (short)a2, (short)a3);
            short4 lv = make_short4((short)f2bf(hx - bf2f(a0)), (short)f2bf(hy - bf2f(a1)),
                                    (short)f2bf(hz - bf2f(a2)), (short)f2bf(hw - bf2f(a3)));
            *(short4*)&h0h[pt * LDB + j0] = hv;
            *(short4*)&h0l[pt * LDB + j0] = lv;
        }
    }
    __syncthreads();

    // ---- hidden layers via MFMA: C[f_out][pt] = W^T x H ----
    unsigned short* curh = h0h; unsigned short* curl = h0l;
    unsigned short* nxth = h1h; unsigned short* nxtl = h1l;

    for (int layer = 0; layer < NHID; ++layer) {
        // B-frags: this wave's 16 points, all 4 k-steps, hi+lo
        short8v afh[4], afl[4];
        const int rb = (ptile * 16 + arow) * LDB;
#pragma unroll
        for (int s = 0; s < 4; ++s) {
            afh[s] = *(const short8v*)&curh[rb + s * 32 + kg * 8];
            afl[s] = *(const short8v*)&curl[rb + s * 32 + kg * 8];
        }

        const unsigned short* whL = whp + (size_t)layer * 16384;
        const unsigned short* wlL = wlp + (size_t)layer * 16384;

#pragma unroll
        for (int mi = 0; mi < 2; ++mi) {
            const int mt = fg * 2 + mi;
            f32x4 acc = *(const f32x4*)&bh[layer * F + mt * 16 + kg * 4];
#pragma unroll
            for (int s = 0; s < 4; ++s) {
                size_t off = ((size_t)((s * 8 + mt) * 64 + lane)) * 8;
                short8v wfh = *(const short8v*)(whL + off);
                short8v wfl = *(const short8v*)(wlL + off);
                acc = __builtin_amdgcn_mfma_f32_16x16x32_bf16(wfh, afh[s], acc, 0, 0, 0);
                acc = __builtin_amdgcn_mfma_f32_16x16x32_bf16(wfl, afh[s], acc, 0, 0, 0);
                acc = __builtin_amdgcn_mfma_f32_16x16x32_bf16(wfh, afl[s], acc, 0, 0, 0);
            }
            // ReLU + hi/lo split; C reg r -> f_out = mt*16 + kg*4 + r, pt = ptile*16 + arow
            float v0 = fmaxf(acc[0], 0.f), v1 = fmaxf(acc[1], 0.f);
            float v2 = fmaxf(acc[2], 0.f), v3 = fmaxf(acc[3], 0.f);
            unsigned short x0 = f2bf(v0), x1 = f2bf(v1), x2 = f2bf(v2), x3 = f2bf(v3);
            short4 hv = make_short4((short)x0, (short)x1, (short)x2, (short)x3);
            short4 lv = make_short4((short)f2bf(v0 - bf2f(x0)), (short)f2bf(v1 - bf2f(x1)),
                                    (short)f2bf(v2 - bf2f(x2)), (short)f2bf(v3 - bf2f(x3)));
            int wadr = (ptile * 16 + arow) * LDB + mt * 16 + kg * 4;
            *(short4*)&nxth[wadr] = hv;
            *(short4*)&nxtl[wadr] = lv;
        }
        __syncthreads();
        unsigned short* t;
        t = curh; curh = nxth; nxth = t;
        t = curl; curl = nxtl; nxtl = t;
    }

    // ---- final layer 128->3: 768 threads, 4-way k-split + shfl reduce ----
    if (tid < 768) {
        int pt = tid >> 4;              // wait: need pt*12 mapping; use div
        pt = tid / 12;
        int rem = tid - pt * 12;
        int c = rem >> 2;
        int ks = rem & 3;
        float acc = 0.f;
        int rb = pt * LDB + ks * 32;
#pragma unroll
        for (int q = 0; q < 4; ++q) {
            short8v h8 = *(const short8v*)&curh[rb + q * 8];
            short8v l8 = *(const short8v*)&curl[rb + q * 8];
#pragma unroll
            for (int j = 0; j < 8; ++j) {
                float hv = bf2f((unsigned short)h8[j]) + bf2f((unsigned short)l8[j]);
                acc = fmaf(hv, Wl[(ks * 32 + q * 8 + j) * 3 + c], acc);
            }
        }
        acc += __shfl_down(acc, 1);
        acc += __shfl_down(acc, 2);
        if (ks == 0) {
            int gp = p0 + pt;
            if (gp < N)
                outp[gp * 3 + c] = inp[gp * 3 + c] + sign * (acc + bl[c]);
        }
    }
}

// ---------------- spatial grid helpers ----------------
__device__ inline int cell_of(float x, float y, float z)
{
    int cx = (int)floorf((x - GLO) * GINV);
    int cy = (int)floorf((y - GLO) * GINV);
    int cz = (int)floorf((z - GLO) * GINV);
    cx = min(max(cx, 0), GM - 1);
    cy = min(max(cy, 0), GM - 1);
    cz = min(max(cz, 0), GM - 1);
    return (cz * GM + cy) * GM + cx;
}

__device__ inline const float* cloud_ptr(int g, const float* g0, const float* g1,
                                         const float* g2, const float* g3)
{
    return g == 0 ? g0 : (g == 1 ? g1 : (g == 2 ? g2 : g3));
}

__global__ __launch_bounds__(256) void zero_counts(int* __restrict__ counts)
{
    counts[blockIdx.x * 256 + threadIdx.x] = 0;
}

__global__ __launch_bounds__(256) void grid_count(
    const float* __restrict__ B, const float* __restrict__ A,
    const float* __restrict__ D, const float* __restrict__ C,
    int* __restrict__ counts, int n)
{
    int g = blockIdx.y;
    const float* P = cloud_ptr(g, B, A, D, C);
    int i = blockIdx.x * 256 + threadIdx.x;
    if (i < n) {
        float x = P[i * 3 + 0], y = P[i * 3 + 1], z = P[i * 3 + 2];
        atomicAdd(&counts[g * GM3 + cell_of(x, y, z)], 1);
    }
}

__global__ __launch_bounds__(256) void scan1(
    const int* __restrict__ counts, int* __restrict__ offs, int* __restrict__ bsum)
{
    int tid = threadIdx.x;
    int i = blockIdx.x * 256 + tid;
    int v = counts[i];
    __shared__ int s[256];
    s[tid] = v;
    __syncthreads();
#pragma unroll
    for (int off = 1; off < 256; off <<= 1) {
        int t = (tid >= off) ? s[tid - off] : 0;
        __syncthreads();
        s[tid] += t;
        __syncthreads();
    }
    offs[i] = s[tid] - v;           // exclusive
    if (tid == 255) bsum[blockIdx.x] = s[255];
}

__global__ __launch_bounds__(256) void scan2(int* __restrict__ bsum)
{
    const int SEG = SCAN_BLKS;      // 432
    int base = blockIdx.x * SEG;
    int t = threadIdx.x;
    int i0 = 2 * t, i1 = 2 * t + 1;
    int e0 = (i0 < SEG) ? bsum[base + i0] : 0;
    int e1 = (i1 < SEG) ? bsum[base + i1] : 0;
    int sum = e0 + e1;
    __shared__ int s[256];
    s[t] = sum;
    __syncthreads();
#pragma unroll
    for (int off = 1; off < 256; off <<= 1) {
        int x = (t >= off) ? s[t - off] : 0;
        __syncthreads();
        s[t] += x;
        __syncthreads();
    }
    int excl = s[t] - sum;
    if (i0 < SEG) bsum[base + i0] = excl;
    if (i1 < SEG) bsum[base + i1] = excl + e0;
}

// scan3 also re-zeros counts (cursors for grid_fill)
__global__ __launch_bounds__(256) void scan3(
    int* __restrict__ offs, const int* __restrict__ bsum, int* __restrict__ counts)
{
    int i = blockIdx.x * 256 + threadIdx.x;
    offs[i] += bsum[blockIdx.x];
    counts[i] = 0;
}

__global__ __launch_bounds__(256) void grid_fill(
    const float* __restrict__ B, const float* __restrict__ A,
    const float* __restrict__ D, const float* __restrict__ C,
    const int* __restrict__ offs, int* __restrict__ counts,
    float4* __restrict__ pts, int n)
{
    int g = blockIdx.y;
    const float* P = cloud_ptr(g, B, A, D, C);
    int i = blockIdx.x * 256 + threadIdx.x;
    if (i < n) {
        float x = P[i * 3 + 0], y = P[i * 3 + 1], z = P[i * 3 + 2];
        int c = g * GM3 + cell_of(x, y, z);
        int slot = offs[c] + atomicAdd(&counts[c], 1);
        pts[(size_t)g * n + slot] = make_float4(x, y, z, 0.f);
    }
}

__global__ __launch_bounds__(64) void grid_search(
    const float* __restrict__ A, const float* __restrict__ B,
    const float* __restrict__ C, const float* __restrict__ D,
    const int* __restrict__ offs, const int* __restrict__ counts,
    const float4* __restrict__ pts, float* __restrict__ mins, int n)
{
    int d = blockIdx.y;
    const float* Q = cloud_ptr(d, A, B, C, D);
    int g = d;
    int i = blockIdx.x * 64 + threadIdx.x;
    if (i >= n) return;
    float qx = Q[i * 3 + 0], qy = Q[i * 3 + 1], qz = Q[i * 3 + 2];
    int cx = min(max((int)floorf((qx - GLO) * GINV), 0), GM - 1);
    int cy = min(max((int)floorf((qy - GLO) * GINV), 0), GM - 1);
    int cz = min(max((int)floorf((qz - GLO) * GINV), 0), GM - 1);
    const int* ofs = offs + (size_t)g * GM3;
    const int* cnt = counts + (size_t)g * GM3;
    const float4* P = pts + (size_t)g * n;
    float mn = 3.4e38f;
    int x0 = max(cx - 1, 0), x1 = min(cx + 1, GM - 1);
#pragma unroll
    for (int dz = -1; dz <= 1; ++dz) {
        int z = cz + dz;
        if ((unsigned)z >= GM) continue;
#pragma unroll
        for (int dy = -1; dy <= 1; ++dy) {
            int y = cy + dy;
            if ((unsigned)y >= GM) continue;
            int rowbase = (z * GM + y) * GM;
            int o = ofs[rowbase + x0];
            int e = ofs[rowbase + x1] + cnt[rowbase + x1];
            for (int k = o; k < e; ++k) {
                float4 p = P[k];
                float ddx = qx - p.x, ddy = qy - p.y, ddz = qz - p.z;
                float dd = fmaf(ddx, ddx, fmaf(ddy, ddy, ddz * ddz));
                mn = fminf(mn, dd);
            }
        }
    }
    mins[(size_t)d * n + i] = (mn < TRUNC_) ? mn : 0.f;
}

// ---------------- reductions ----------------
__device__ inline float block_sum256(float v)
{
    __shared__ float sws[4];
#pragma unroll
    for (int o = 32; o > 0; o >>= 1) v += __shfl_down(v, o, 64);
    int w = threadIdx.x >> 6;
    if ((threadIdx.x & 63) == 0) sws[w] = v;
    __syncthreads();
    if (threadIdx.x == 0) v = sws[0] + sws[1] + sws[2] + sws[3];
    return v;
}

__global__ __launch_bounds__(256) void reduce1_kernel(
    const float* __restrict__ mins, float* __restrict__ partials, int total)
{
    float s = 0.f;
    for (int idx = blockIdx.x * blockDim.x + threadIdx.x; idx < total;
         idx += gridDim.x * blockDim.x)
        s += mins[idx];
    float bs = block_sum256(s);
    if (threadIdx.x == 0) partials[blockIdx.x] = bs;
}

__global__ __launch_bounds__(256) void reduce2_kernel(
    const float* __restrict__ partials, int nb, float* __restrict__ out, float inv)
{
    float s = 0.f;
    for (int i = threadIdx.x; i < nb; i += blockDim.x) s += partials[i];
    float bs = block_sum256(s);
    if (threadIdx.x == 0) out[0] = bs * inv;
}

// ---------------- launch ----------------
extern "C" void kernel_launch(void* const* d_in, const int* in_sizes, int n_in,
                              void* d_out, int out_size, void* d_ws, size_t ws_size,
                              hipStream_t stream)
{
    const float* pc0 = (const float*)d_in[0];
    const float* pc1 = (const float*)d_in[1];
    const float* W0  = (const float*)d_in[2];
    const float* b0  = (const float*)d_in[3];
    const float* Wh  = (const float*)d_in[4];
    const float* bh  = (const float*)d_in[5];
    const float* Wl  = (const float*)d_in[6];
    const float* bl  = (const float*)d_in[7];
    const float* W0i = (const float*)d_in[8];
    const float* b0i = (const float*)d_in[9];
    const float* Whi = (const float*)d_in[10];
    const float* bhi = (const float*)d_in[11];
    const float* Wli = (const float*)d_in[12];
    const float* bli = (const float*)d_in[13];
    float* out = (float*)d_out;

    const int N = in_sizes[0] / 3;   // 20000

    // ws layout (byte offsets)
    char* base = (char*)d_ws;
    float*  A        = (float*)(base + 0);               // 240000
    float*  C        = (float*)(base + 240000);          // 240000
    int*    counts   = (int*)  (base + 480000);          // 1769472
    int*    offs     = (int*)  (base + 2249472);         // 1769472
    int*    bsum     = (int*)  (base + 4018944);         // 6912
    float4* pts      = (float4*)(base + 4025856);        // 1280000
    float*  mins     = (float*)(base + 5305856);         // 320000
    float*  partials = (float*)(base + 5625856);         // 320
    unsigned short* whp = (unsigned short*)(base + 5626176); // 458752
    unsigned short* wlp = (unsigned short*)(base + 6084928); // 458752

    const int NB1 = 80;
    const int PB = (N + 255) / 256;        // 79
    const int SB = (N + 63) / 64;          // 313
    const int ZB = NGRID * GM3 / 256;      // 1728
    const int PACKB = (14 * 4 * 8 * 64 * 8) / 256;  // 896

    // pack weights into MFMA A-frag (W^T) hi/lo order (both MLPs)
    hipLaunchKernelGGL(pack_w_kernel, dim3(PACKB), dim3(256), 0, stream,
                       Wh, Whi, whp, wlp);

    int mlpg = (N + BP - 1) / BP;  // 313
    hipLaunchKernelGGL(mlp_mfma_kernel, dim3(mlpg), dim3(1024), 0, stream,
                       pc0, W0, b0, whp, wlp, bh, Wl, bl, A, 1.0f, N);
    hipLaunchKernelGGL(mlp_mfma_kernel, dim3(mlpg), dim3(1024), 0, stream,
                       A, W0i, b0i, whp + 7 * 16384, wlp + 7 * 16384, bhi, Wli, bli,
                       C, -1.0f, N);

    // build 4 grids: g0=pc1, g1=A, g2=pc0, g3=C
    hipLaunchKernelGGL(zero_counts, dim3(ZB), dim3(256), 0, stream, counts);
    hipLaunchKernelGGL(grid_count, dim3(PB, NGRID), dim3(256), 0, stream,
                       pc1, A, pc0, C, counts, N);
    hipLaunchKernelGGL(scan1, dim3(ZB), dim3(256), 0, stream, counts, offs, bsum);
    hipLaunchKernelGGL(scan2, dim3(NGRID), dim3(256), 0, stream, bsum);
    hipLaunchKernelGGL(scan3, dim3(ZB), dim3(256), 0, stream, offs, bsum, counts);
    hipLaunchKernelGGL(grid_fill, dim3(PB, NGRID), dim3(256), 0, stream,
                       pc1, A, pc0, C, offs, counts, pts, N);

    hipLaunchKernelGGL(grid_search, dim3(SB, NGRID), dim3(64), 0, stream,
                       A, pc1, C, pc0, offs, counts, pts, mins, N);

    hipLaunchKernelGGL(reduce1_kernel, dim3(NB1), dim3(256), 0, stream,
                       mins, partials, 4 * N);
    hipLaunchKernelGGL(reduce2_kernel, dim3(1), dim3(256), 0, stream,
                       partials, NB1, out, 1.0f / (float)N);
}